// Round 7
// baseline (9212.934 us; speedup 1.0000x reference)
//
#include <hip/hip_runtime.h>
#include <math.h>

#define H   512
#define S   64
#define T   128
#define NB  128
#define L   512

// workspace layout (float elements)
#define OFF_ENC   0u               // enc_out [N][L][H]  33,554,432
#define OFF_Q     33554432u        // q_all   [T][N][H]   8,388,608
#define OFF_ATTN  41943040u        // attn    [T][N][H]   8,388,608
#define OFF_DGI   50331648u        // dgi     [S][1536]      98,304
#define OFF_M4    50429952u        // M packed [k4][s][4]    65,536
#define OFF_C     50495488u        // c[64]
#define OFF_FLG1  50495552u        // enc flags: 16 groups x 16 slots x 32 ints = 8192
#define OFF_FLG2  50503744u        // dec flags: 8192

// output layout (float elements)
#define OUT_V  0
#define OUT_HN 1048576
#define OUT_W  1114112

__device__ __forceinline__ float sigmoidf_(float x){ return 1.0f/(1.0f+expf(-x)); }

#define FLAG_ST(p, v) __hip_atomic_store((p), (v), __ATOMIC_RELAXED, __HIP_MEMORY_SCOPE_AGENT)
#define FLAG_LD(p)    __hip_atomic_load((p), __ATOMIC_RELAXED, __HIP_MEMORY_SCOPE_AGENT)
// coherent float ld/st: write-through / L2-bypass, no fences needed
#define ATOM_STF(p, v) __hip_atomic_store((p), (v), __ATOMIC_RELAXED, __HIP_MEMORY_SCOPE_AGENT)
#define ATOM_LDF(p)    __hip_atomic_load((p), __ATOMIC_RELAXED, __HIP_MEMORY_SCOPE_AGENT)

// volatile-asm load: result cannot be rematerialized/sunk -> stays in VGPRs
#define GLOAD4(dst, addr) \
  asm volatile("global_load_dwordx4 %0, %1, off" : "=v"(dst) : "v"(addr))

// ---------------- prep: M[k][s] = sum_o affW[o][k]*fcW[s][o]; c[s] ----------------
__global__ void prep_m_kernel(float* __restrict__ M4, float* __restrict__ c,
                              const float* __restrict__ aW, const float* __restrict__ aB,
                              const float* __restrict__ fcW, const float* __restrict__ fcB){
  int idx = blockIdx.x*256 + threadIdx.x;   // 65536 = 1024k x 64s
  int k = idx >> 6, s = idx & 63;
  float acc = 0.f;
  for (int o = 0; o < H; ++o) acc += aW[(size_t)o*1024 + k] * fcW[(size_t)s*H + o];
  int k4 = k >> 2, kk = k & 3;
  M4[(size_t)(k4*64 + s)*4 + kk] = acc;
  if (idx < 64){
    float a2 = 0.f;
    for (int o = 0; o < H; ++o) a2 += aB[o] * fcW[(size_t)idx*H + o];
    c[idx] = a2 + fcB[idx];
  }
}

// ---------------- prep: dgi[s][j] = dec_Wih[j]·emb[s] + dec_bih[j] ----------------
__global__ __launch_bounds__(256) void dgi_kernel(
    float* __restrict__ dgi, const float* __restrict__ Wih,
    const float* __restrict__ bih, const float* __restrict__ emb){
  __shared__ __align__(16) float wsm[4][H];
  int b = blockIdx.x;               // 64 blocks x 24 j each
  int tid = threadIdx.x;
  int jl = tid >> 6, s = tid & 63;
  for (int jj = 0; jj < 6; ++jj){
    int j0 = b*24 + jj*4;
    __syncthreads();
    for (int e = tid; e < 512; e += 256){
      int r = e >> 7, kv = e & 127;
      ((float4*)&wsm[r][0])[kv] = *(const float4*)&Wih[(size_t)(j0+r)*H + kv*4];
    }
    __syncthreads();
    int j = j0 + jl;
    float acc = bih[j];
    #pragma unroll 4
    for (int k4 = 0; k4 < 128; ++k4){
      float4 w4 = ((const float4*)&wsm[jl][0])[k4];
      float4 e4 = *(const float4*)&emb[(size_t)s*H + k4*4];
      acc = fmaf(w4.x,e4.x, fmaf(w4.y,e4.y, fmaf(w4.z,e4.z, fmaf(w4.w,e4.w, acc))));
    }
    dgi[(size_t)s*1536 + j] = acc;
  }
}

// ============ persistent encoder: 16 n-groups x 16 j-blocks ============
// block 512 thr = 32 jh x 16 kg; 8 rows/group. weights 24 f4 = 96 VGPR (pinned).
// h transfer: write-through atomic stores + coherent atomic-load staging.
// two-phase staging pipelines poll/load latency; single barrier before compute.
__global__ __launch_bounds__(512,2) void enc_persist(
    float* __restrict__ enc, const float* __restrict__ x,
    const float* __restrict__ Wih, const float* __restrict__ Whh,
    const float* __restrict__ bih, const float* __restrict__ bhh,
    int* __restrict__ flags){
  __shared__ __align__(16) float hs[8*H];     // 16 KB
  float4* hs4 = (float4*)hs;
  const int tid = threadIdx.x;
  const int jh_l = tid >> 4;            // 0..31
  const int kg   = tid & 15;            // 0..15
  const int g  = blockIdx.x & 15;       // n-group
  const int jb = blockIdx.x >> 4;       // j-block 0..15
  const int jh = jb*32 + jh_l;
  const int n0 = g*8;
  int* fl = flags + g*16*32;            // 16 flags, 128B apart

  float4 wr[8], wz[8], wn[8];
  #pragma unroll
  for (int i = 0; i < 8; ++i){
    const float* p0 = &Whh[(size_t)jh*H        + (kg + 16*i)*4];
    const float* p1 = &Whh[(size_t)(512+jh)*H  + (kg + 16*i)*4];
    const float* p2 = &Whh[(size_t)(1024+jh)*H + (kg + 16*i)*4];
    GLOAD4(wr[i], p0);
    GLOAD4(wz[i], p1);
    GLOAD4(wn[i], p2);
  }
  asm volatile("s_waitcnt vmcnt(0)" ::: "memory");

  const float wir0 = Wih[jh*2],        wir1 = Wih[jh*2+1];
  const float wiz0 = Wih[(512+jh)*2],  wiz1 = Wih[(512+jh)*2+1];
  const float win0 = Wih[(1024+jh)*2], win1 = Wih[(1024+jh)*2+1];
  const float br  = bih[jh] + bhh[jh];
  const float bz  = bih[512+jh] + bhh[512+jh];
  const float bin = bih[1024+jh], bhn = bhh[1024+jh];
  const int nr = kg & 7;
  const int n = n0 + nr;
  const int sr = tid >> 6;              // stage row 0..7
  const int sc = tid & 63;              // stage f4-col 0..63

  for (int t = 0; t < L; ++t){
    float x0 = x[(size_t)n*1024 + t], x1 = x[(size_t)n*1024 + 512 + t];
    if (t == 0){
      for (int e = tid; e < 1024; e += 512) hs4[e] = make_float4(0,0,0,0);
      __syncthreads();
    } else {
      #pragma unroll
      for (int ph = 0; ph < 2; ++ph){
        if (tid == 0){
          #pragma unroll
          for (int b = ph*8; b < ph*8+8; ++b)
            while (FLAG_LD(&fl[b*32]) < t) __builtin_amdgcn_s_sleep(1);
        }
        __syncthreads();
        const float* src = &enc[((size_t)(n0+sr)*L + (t-1))*H + ph*256 + sc*4];
        float a0 = ATOM_LDF(src), a1 = ATOM_LDF(src+1);
        float a2 = ATOM_LDF(src+2), a3 = ATOM_LDF(src+3);
        hs4[sr*128 + ph*64 + sc] = make_float4(a0,a1,a2,a3);
      }
      __syncthreads();
    }

    float mar = 0.f, maz = 0.f, man = 0.f;
    #pragma unroll
    for (int nl = 0; nl < 8; ++nl){
      float pr = 0.f, pz = 0.f, pn = 0.f;
      #pragma unroll
      for (int i = 0; i < 8; ++i){
        float4 h4 = hs4[nl*128 + i*16 + kg];
        pr = fmaf(h4.x,wr[i].x, fmaf(h4.y,wr[i].y, fmaf(h4.z,wr[i].z, fmaf(h4.w,wr[i].w, pr))));
        pz = fmaf(h4.x,wz[i].x, fmaf(h4.y,wz[i].y, fmaf(h4.z,wz[i].z, fmaf(h4.w,wz[i].w, pz))));
        pn = fmaf(h4.x,wn[i].x, fmaf(h4.y,wn[i].y, fmaf(h4.z,wn[i].z, fmaf(h4.w,wn[i].w, pn))));
      }
      #pragma unroll
      for (int off = 1; off < 16; off <<= 1){
        pr += __shfl_xor(pr, off);
        pz += __shfl_xor(pz, off);
        pn += __shfl_xor(pn, off);
      }
      if (kg == nl){ mar = pr; maz = pz; man = pn; }
    }
    if (kg < 8){
      float rg = sigmoidf_(fmaf(x0,wir0, fmaf(x1,wir1, br))  + mar);
      float zg = sigmoidf_(fmaf(x0,wiz0, fmaf(x1,wiz1, bz))  + maz);
      float ng = tanhf    (fmaf(x0,win0, fmaf(x1,win1, bin)) + rg*(man + bhn));
      float hp = hs[nr*H + jh];
      ATOM_STF(&enc[((size_t)n*L + t)*H + jh], (1.f - zg)*ng + zg*hp);
    }
    __syncthreads();                    // drains each wave's stores (vmcnt) pre-barrier
    if (tid == 0){
      __threadfence();                  // cheap: no dirty lines (write-through stores)
      FLAG_ST(&fl[jb*32], t+1);
    }
  }
}

// ============ persistent decoder: same structure, Wih·emb pre-tabulated ============
__global__ __launch_bounds__(512,2) void dec_persist(
    const float* __restrict__ enc, float* __restrict__ q_all,
    const int* __restrict__ tgt, const float* __restrict__ dgi,
    const float* __restrict__ Whh, const float* __restrict__ bhh,
    float* __restrict__ hn_out, int* __restrict__ flags){
  __shared__ __align__(16) float hs[8*H];
  float4* hs4 = (float4*)hs;
  const int tid = threadIdx.x;
  const int jh_l = tid >> 4;
  const int kg   = tid & 15;
  const int g  = blockIdx.x & 15;
  const int jb = blockIdx.x >> 4;
  const int jh = jb*32 + jh_l;
  const int n0 = g*8;
  int* fl = flags + g*16*32;

  float4 wr[8], wz[8], wn[8];
  #pragma unroll
  for (int i = 0; i < 8; ++i){
    const float* p0 = &Whh[(size_t)jh*H        + (kg + 16*i)*4];
    const float* p1 = &Whh[(size_t)(512+jh)*H  + (kg + 16*i)*4];
    const float* p2 = &Whh[(size_t)(1024+jh)*H + (kg + 16*i)*4];
    GLOAD4(wr[i], p0);
    GLOAD4(wz[i], p1);
    GLOAD4(wn[i], p2);
  }
  asm volatile("s_waitcnt vmcnt(0)" ::: "memory");

  const float bh_r = bhh[jh], bh_z = bhh[512+jh], bh_n = bhh[1024+jh];
  const int nr = kg & 7;
  const int n = n0 + nr;
  const int sr = tid >> 6;
  const int sc = tid & 63;

  for (int t = 0; t < T; ++t){
    int tok = (t == 0) ? 0 : tgt[n*T + (t-1)];
    float g0 = dgi[(size_t)tok*1536 + jh];
    float g1 = dgi[(size_t)tok*1536 + 512 + jh];
    float g2 = dgi[(size_t)tok*1536 + 1024 + jh];

    #pragma unroll
    for (int ph = 0; ph < 2; ++ph){
      if (tid == 0 && t > 0){
        #pragma unroll
        for (int b = ph*8; b < ph*8+8; ++b)
          while (FLAG_LD(&fl[b*32]) < t) __builtin_amdgcn_s_sleep(1);
      }
      __syncthreads();
      const float* src = (t == 0)
          ? &enc[((size_t)(n0+sr)*L + (L-1))*H + ph*256 + sc*4]
          : &q_all[(size_t)(t-1)*NB*H + (size_t)(n0+sr)*H + ph*256 + sc*4];
      float a0 = ATOM_LDF(src), a1 = ATOM_LDF(src+1);
      float a2 = ATOM_LDF(src+2), a3 = ATOM_LDF(src+3);
      hs4[sr*128 + ph*64 + sc] = make_float4(a0,a1,a2,a3);
    }
    __syncthreads();

    float mar = 0.f, maz = 0.f, man = 0.f;
    #pragma unroll
    for (int nl = 0; nl < 8; ++nl){
      float pr = 0.f, pz = 0.f, pn = 0.f;
      #pragma unroll
      for (int i = 0; i < 8; ++i){
        float4 h4 = hs4[nl*128 + i*16 + kg];
        pr = fmaf(h4.x,wr[i].x, fmaf(h4.y,wr[i].y, fmaf(h4.z,wr[i].z, fmaf(h4.w,wr[i].w, pr))));
        pz = fmaf(h4.x,wz[i].x, fmaf(h4.y,wz[i].y, fmaf(h4.z,wz[i].z, fmaf(h4.w,wz[i].w, pz))));
        pn = fmaf(h4.x,wn[i].x, fmaf(h4.y,wn[i].y, fmaf(h4.z,wn[i].z, fmaf(h4.w,wn[i].w, pn))));
      }
      #pragma unroll
      for (int off = 1; off < 16; off <<= 1){
        pr += __shfl_xor(pr, off);
        pz += __shfl_xor(pz, off);
        pn += __shfl_xor(pn, off);
      }
      if (kg == nl){ mar = pr; maz = pz; man = pn; }
    }
    if (kg < 8){
      float rg = sigmoidf_(g0 + mar + bh_r);
      float zg = sigmoidf_(g1 + maz + bh_z);
      float ng = tanhf    (g2 + rg*(man + bh_n));
      float hp = hs[nr*H + jh];
      float q  = (1.f - zg)*ng + zg*hp;
      ATOM_STF(&q_all[(size_t)t*NB*H + (size_t)n*H + jh], q);
      if (t == T-1) hn_out[(size_t)n*H + jh] = q;
    }
    __syncthreads();
    if (tid == 0){
      __threadfence();
      FLAG_ST(&fl[jb*32], t+1);
    }
  }
}

// ---------------- batched scores: s[n][t][l] = q[t][n][:] . enc[n][l][:] ------------
__global__ __launch_bounds__(256) void scores_kernel(
    const float* __restrict__ enc, const float* __restrict__ q_all,
    float* __restrict__ wout){
  int t0 = blockIdx.x * 16, l0 = blockIdx.y * 64, n = blockIdx.z;
  int tid = threadIdx.x;
  __shared__ __align__(16) float A[16][33];
  __shared__ __align__(16) float B[32][68];
  int t_l = tid >> 4, l_g = tid & 15;
  float4 acc = make_float4(0,0,0,0);
  for (int kc = 0; kc < 16; ++kc){
    __syncthreads();
    for (int e = tid; e < 512; e += 256){
      int r = e >> 5, k = e & 31;
      A[r][k] = q_all[(size_t)(t0+r)*NB*H + (size_t)n*H + kc*32 + k];
    }
    for (int e = tid; e < 2048; e += 256){
      int l = e >> 5, k = e & 31;
      B[k][l] = enc[((size_t)n*L + l0 + l)*H + kc*32 + k];
    }
    __syncthreads();
    #pragma unroll
    for (int kk = 0; kk < 32; ++kk){
      float a = A[t_l][kk];
      float4 b = *(const float4*)&B[kk][l_g*4];
      acc.x += a*b.x; acc.y += a*b.y; acc.z += a*b.z; acc.w += a*b.w;
    }
  }
  *(float4*)&wout[(size_t)n*T*L + (size_t)(t0+t_l)*L + l0 + l_g*4] = acc;
}

// ---------------- softmax rows of all_w in place (one wave per (n,t)) --------------
__global__ __launch_bounds__(64) void softmax_kernel(float* __restrict__ w){
  float* p = w + (size_t)blockIdx.x * L;
  int lane = threadIdx.x;
  float4 v0 = *(float4*)&p[lane*8];
  float4 v1 = *(float4*)&p[lane*8+4];
  float m = fmaxf(fmaxf(fmaxf(v0.x,v0.y),fmaxf(v0.z,v0.w)),
                  fmaxf(fmaxf(v1.x,v1.y),fmaxf(v1.z,v1.w)));
  for (int off = 32; off; off >>= 1) m = fmaxf(m, __shfl_xor(m, off));
  v0.x = expf(v0.x-m); v0.y = expf(v0.y-m); v0.z = expf(v0.z-m); v0.w = expf(v0.w-m);
  v1.x = expf(v1.x-m); v1.y = expf(v1.y-m); v1.z = expf(v1.z-m); v1.w = expf(v1.w-m);
  float s = v0.x+v0.y+v0.z+v0.w+v1.x+v1.y+v1.z+v1.w;
  for (int off = 32; off; off >>= 1) s += __shfl_xor(s, off);
  float inv = 1.f/s;
  v0.x*=inv; v0.y*=inv; v0.z*=inv; v0.w*=inv;
  v1.x*=inv; v1.y*=inv; v1.z*=inv; v1.w*=inv;
  *(float4*)&p[lane*8] = v0;
  *(float4*)&p[lane*8+4] = v1;
}

// ---------------- batched attn: a[t][n][h] = sum_l w[n][t][l] * enc[n][l][h] -------
__global__ __launch_bounds__(256) void attn_kernel(
    const float* __restrict__ enc, const float* __restrict__ w_in,
    float* __restrict__ attn_all){
  int t0 = blockIdx.x * 16, h0 = blockIdx.y * 64, n = blockIdx.z;
  int tid = threadIdx.x;
  __shared__ __align__(16) float A[16][33];
  __shared__ __align__(16) float B[32][64];
  int t_l = tid >> 4, h_g = tid & 15;
  float4 acc = make_float4(0,0,0,0);
  for (int lc = 0; lc < 16; ++lc){
    __syncthreads();
    for (int e = tid; e < 512; e += 256){
      int r = e >> 5, ll = e & 31;
      A[r][ll] = w_in[(size_t)n*T*L + (size_t)(t0+r)*L + lc*32 + ll];
    }
    for (int e = tid; e < 2048; e += 256){
      int ll = e >> 6, h = e & 63;
      B[ll][h] = enc[((size_t)n*L + lc*32 + ll)*H + h0 + h];
    }
    __syncthreads();
    #pragma unroll
    for (int ll = 0; ll < 32; ++ll){
      float a = A[t_l][ll];
      float4 b = *(const float4*)&B[ll][h_g*4];
      acc.x += a*b.x; acc.y += a*b.y; acc.z += a*b.z; acc.w += a*b.w;
    }
  }
  *(float4*)&attn_all[(size_t)(t0+t_l)*NB*H + (size_t)n*H + h0 + h_g*4] = acc;
}

// ---------------- output head: v[n][t][s] = c[s] + [q|attn] . M[:,s] ----------------
__global__ __launch_bounds__(256) void out_kernel(
    const float* __restrict__ q_all, const float* __restrict__ attn_all,
    const float4* __restrict__ M4, const float* __restrict__ c,
    float* __restrict__ vout){
  __shared__ __align__(16) float cat[4][1024];
  int tid = threadIdx.x;
  int row0 = blockIdx.x * 4;
  for (int e = tid; e < 4096; e += 256){
    int r = e >> 10, k = e & 1023;
    int row = row0 + r;
    int n = row >> 7, t = row & 127;
    cat[r][k] = (k < 512) ? q_all[(size_t)t*NB*H + (size_t)n*H + k]
                          : attn_all[(size_t)t*NB*H + (size_t)n*H + (k-512)];
  }
  __syncthreads();
  int r_l = tid >> 6, s = tid & 63;
  int row = row0 + r_l;
  int n = row >> 7, t = row & 127;
  float acc = c[s];
  #pragma unroll 4
  for (int k4 = 0; k4 < 256; ++k4){
    float4 cv = ((const float4*)&cat[r_l][0])[k4];
    float4 m = M4[k4*64 + s];
    acc += cv.x*m.x + cv.y*m.y + cv.z*m.z + cv.w*m.w;
  }
  vout[(size_t)n*T*S + (size_t)t*S + s] = acc;
}

extern "C" void kernel_launch(void* const* d_in, const int* in_sizes, int n_in,
                              void* d_out, int out_size, void* d_ws, size_t ws_size,
                              hipStream_t stream) {
  const float* x       = (const float*)d_in[0];
  const int*   target  = (const int*)d_in[1];
  const float* enc_Wih = (const float*)d_in[2];
  const float* enc_Whh = (const float*)d_in[3];
  const float* enc_bih = (const float*)d_in[4];
  const float* enc_bhh = (const float*)d_in[5];
  const float* dec_Wih = (const float*)d_in[6];
  const float* dec_Whh = (const float*)d_in[7];
  const float* dec_bih = (const float*)d_in[8];
  const float* dec_bhh = (const float*)d_in[9];
  const float* emb     = (const float*)d_in[10];
  const float* affW    = (const float*)d_in[11];
  const float* affB    = (const float*)d_in[12];
  const float* fcW     = (const float*)d_in[13];
  const float* fcB     = (const float*)d_in[14];

  float* ws      = (float*)d_ws;
  float* enc     = ws + OFF_ENC;
  float* q_all   = ws + OFF_Q;
  float* attn_al = ws + OFF_ATTN;
  float* dgi     = ws + OFF_DGI;
  float* M4f     = ws + OFF_M4;
  float* cb      = ws + OFF_C;
  int*   flg1    = (int*)(ws + OFF_FLG1);
  int*   flg2    = (int*)(ws + OFF_FLG2);

  float* vout   = (float*)d_out + OUT_V;
  float* hn_out = (float*)d_out + OUT_HN;
  float* w_all  = (float*)d_out + OUT_W;

  hipMemsetAsync(flg1, 0, 2*8192*sizeof(int), stream);   // flg1+flg2 contiguous
  prep_m_kernel<<<256, 256, 0, stream>>>(M4f, cb, affW, affB, fcW, fcB);
  dgi_kernel<<<64, 256, 0, stream>>>(dgi, dec_Wih, dec_bih, emb);

  {
    void* args[] = {(void*)&enc, (void*)&x, (void*)&enc_Wih, (void*)&enc_Whh,
                    (void*)&enc_bih, (void*)&enc_bhh, (void*)&flg1};
    hipLaunchCooperativeKernel((void*)enc_persist, dim3(256), dim3(512), args, 0, stream);
  }
  {
    void* args[] = {(void*)&enc, (void*)&q_all, (void*)&target, (void*)&dgi,
                    (void*)&dec_Whh, (void*)&dec_bhh, (void*)&hn_out, (void*)&flg2};
    hipLaunchCooperativeKernel((void*)dec_persist, dim3(256), dim3(512), args, 0, stream);
  }

  scores_kernel<<<dim3(8,8,NB), 256, 0, stream>>>(enc, q_all, w_all);
  softmax_kernel<<<NB*T, 64, 0, stream>>>(w_all);
  attn_kernel<<<dim3(8,8,NB), 256, 0, stream>>>(enc, w_all, attn_al);
  out_kernel<<<NB*T/4, 256, 0, stream>>>(q_all, attn_al, (const float4*)M4f, cb, vout);
}

// Round 8
// 3536.000 us; speedup vs baseline: 2.6055x; 2.6055x over previous
//
#include <hip/hip_runtime.h>
#include <math.h>

#define H   512
#define S   64
#define T   128
#define NB  128
#define L   512

// workspace layout (float elements)
#define OFF_ENC   0u               // enc_out [N][L][H]  33,554,432
#define OFF_Q     33554432u        // q_all   [T][N][H]   8,388,608
#define OFF_ATTN  41943040u        // attn    [T][N][H]   8,388,608
#define OFF_DGI   50331648u        // dgi     [S][1536]      98,304
#define OFF_M4    50429952u        // M packed [k4][s][4]    65,536
#define OFF_C     50495488u        // c[64]
#define OFF_FLG1  50495552u        // enc flags: 32 groups x 8 slots x 32 ints = 8192
#define OFF_FLG2  50503744u        // dec flags: 8192

// output layout (float elements)
#define OUT_V  0
#define OUT_HN 1048576
#define OUT_W  1114112

__device__ __forceinline__ float sigmoidf_(float x){ return 1.0f/(1.0f+expf(-x)); }

#define FLAG_ST(p, v) __hip_atomic_store((p), (v), __ATOMIC_RELAXED, __HIP_MEMORY_SCOPE_AGENT)
#define FLAG_LD(p)    __hip_atomic_load((p), __ATOMIC_RELAXED, __HIP_MEMORY_SCOPE_AGENT)
// IF$-coherent data transfer (no fences needed: r7 empirically proved visibility)
#define ATOM_STF(p, v) __hip_atomic_store((p), (v), __ATOMIC_RELAXED, __HIP_MEMORY_SCOPE_AGENT)
#define ATOM_LD8(p)    __hip_atomic_load((const unsigned long long*)(p), __ATOMIC_RELAXED, __HIP_MEMORY_SCOPE_AGENT)

// volatile-asm load: result cannot be rematerialized -> stays in VGPRs (with 2,2 cap)
#define GLOAD4(dst, addr) \
  asm volatile("global_load_dwordx4 %0, %1, off" : "=v"(dst) : "v"(addr))

// ---------------- prep: M[k][s] = sum_o affW[o][k]*fcW[s][o]; c[s] ----------------
__global__ void prep_m_kernel(float* __restrict__ M4, float* __restrict__ c,
                              const float* __restrict__ aW, const float* __restrict__ aB,
                              const float* __restrict__ fcW, const float* __restrict__ fcB){
  int idx = blockIdx.x*256 + threadIdx.x;   // 65536 = 1024k x 64s
  int k = idx >> 6, s = idx & 63;
  float acc = 0.f;
  for (int o = 0; o < H; ++o) acc += aW[(size_t)o*1024 + k] * fcW[(size_t)s*H + o];
  int k4 = k >> 2, kk = k & 3;
  M4[(size_t)(k4*64 + s)*4 + kk] = acc;
  if (idx < 64){
    float a2 = 0.f;
    for (int o = 0; o < H; ++o) a2 += aB[o] * fcW[(size_t)idx*H + o];
    c[idx] = a2 + fcB[idx];
  }
}

// ---------------- prep: dgi[s][j] = dec_Wih[j]·emb[s] + dec_bih[j] ----------------
__global__ __launch_bounds__(256) void dgi_kernel(
    float* __restrict__ dgi, const float* __restrict__ Wih,
    const float* __restrict__ bih, const float* __restrict__ emb){
  __shared__ __align__(16) float wsm[4][H];
  int b = blockIdx.x;               // 64 blocks x 24 j each
  int tid = threadIdx.x;
  int jl = tid >> 6, s = tid & 63;
  for (int jj = 0; jj < 6; ++jj){
    int j0 = b*24 + jj*4;
    __syncthreads();
    for (int e = tid; e < 512; e += 256){
      int r = e >> 7, kv = e & 127;
      ((float4*)&wsm[r][0])[kv] = *(const float4*)&Wih[(size_t)(j0+r)*H + kv*4];
    }
    __syncthreads();
    int j = j0 + jl;
    float acc = bih[j];
    #pragma unroll 4
    for (int k4 = 0; k4 < 128; ++k4){
      float4 w4 = ((const float4*)&wsm[jl][0])[k4];
      float4 e4 = *(const float4*)&emb[(size_t)s*H + k4*4];
      acc = fmaf(w4.x,e4.x, fmaf(w4.y,e4.y, fmaf(w4.z,e4.z, fmaf(w4.w,e4.w, acc))));
    }
    dgi[(size_t)s*1536 + j] = acc;
  }
}

// ============ persistent encoder: 32 n-groups x 8 j-blocks (r6 skeleton) =====
// block 512 thr = 64 jh x 8 kg; 4 rows/group. weights 48 f4 = 192 VGPR pinned;
// amdgpu_waves_per_eu(2,2) removes the allocator's occupancy incentive to spill.
// h transfer: IF$-coherent atomics both sides, NO fences (r7-proven visibility).
__global__ __attribute__((amdgpu_flat_work_group_size(512,512), amdgpu_waves_per_eu(2,2)))
void enc_persist(
    float* __restrict__ enc, const float* __restrict__ x,
    const float* __restrict__ Wih, const float* __restrict__ Whh,
    const float* __restrict__ bih, const float* __restrict__ bhh,
    int* __restrict__ flags){
  __shared__ __align__(16) float hs[4*H];    // 8 KB: h(t-1) for 4 rows
  const int tid = threadIdx.x;
  const int jh_l = tid >> 3;            // 0..63
  const int kg   = tid & 7;             // 0..7
  const int g  = blockIdx.x & 31;       // n-group; siblings stride 32
  const int jb = blockIdx.x >> 5;       // j-block 0..7
  const int jh = jb*64 + jh_l;
  const int n0 = g*4;
  int* fl = flags + g*8*32;             // 8 flags, 128B apart

  float4 wr[16], wz[16], wn[16];
  #pragma unroll
  for (int i = 0; i < 16; ++i){
    const float* p0 = &Whh[(size_t)jh*H        + (kg + 8*i)*4];
    const float* p1 = &Whh[(size_t)(512+jh)*H  + (kg + 8*i)*4];
    const float* p2 = &Whh[(size_t)(1024+jh)*H + (kg + 8*i)*4];
    GLOAD4(wr[i], p0);
    GLOAD4(wz[i], p1);
    GLOAD4(wn[i], p2);
  }
  asm volatile("s_waitcnt vmcnt(0)" ::: "memory");

  const float wir0 = Wih[jh*2],        wir1 = Wih[jh*2+1];
  const float wiz0 = Wih[(512+jh)*2],  wiz1 = Wih[(512+jh)*2+1];
  const float win0 = Wih[(1024+jh)*2], win1 = Wih[(1024+jh)*2+1];
  const float br  = bih[jh] + bhh[jh];
  const float bz  = bih[512+jh] + bhh[512+jh];
  const float bin = bih[1024+jh], bhn = bhh[1024+jh];
  const int nr = kg & 3;
  const int n = n0 + nr;
  const int sr = tid >> 7;              // stage row 0..3
  const int sv = tid & 127;             // stage 16B-unit 0..127

  for (int t = 0; t < L; ++t){
    float x0 = x[(size_t)n*1024 + t], x1 = x[(size_t)n*1024 + 512 + t];
    if (t == 0){
      ((float4*)hs)[tid] = make_float4(0,0,0,0);
      __syncthreads();
    } else {
      if (tid < 8){
        while (FLAG_LD(&fl[tid*32]) < t) __builtin_amdgcn_s_sleep(1);
      }
      __syncthreads();
      const float* srcp = &enc[((size_t)(n0+sr)*L + (t-1))*H + sv*4];
      unsigned long long a = ATOM_LD8(srcp);
      unsigned long long b = ATOM_LD8(srcp+2);
      unsigned long long* dst = (unsigned long long*)hs;
      dst[(sr*128+sv)*2]   = a;
      dst[(sr*128+sv)*2+1] = b;
      __syncthreads();
    }

    float mar = 0.f, maz = 0.f, man = 0.f;
    #pragma unroll
    for (int nl = 0; nl < 4; ++nl){
      const float4* hb = (const float4*)&hs[nl*H];
      float pr = 0.f, pz = 0.f, pn = 0.f;
      #pragma unroll
      for (int i = 0; i < 16; ++i){
        float4 h4 = hb[kg + 8*i];
        pr = fmaf(h4.x,wr[i].x, fmaf(h4.y,wr[i].y, fmaf(h4.z,wr[i].z, fmaf(h4.w,wr[i].w, pr))));
        pz = fmaf(h4.x,wz[i].x, fmaf(h4.y,wz[i].y, fmaf(h4.z,wz[i].z, fmaf(h4.w,wz[i].w, pz))));
        pn = fmaf(h4.x,wn[i].x, fmaf(h4.y,wn[i].y, fmaf(h4.z,wn[i].z, fmaf(h4.w,wn[i].w, pn))));
      }
      #pragma unroll
      for (int off = 1; off < 8; off <<= 1){
        pr += __shfl_xor(pr, off);
        pz += __shfl_xor(pz, off);
        pn += __shfl_xor(pn, off);
      }
      if (kg == nl){ mar = pr; maz = pz; man = pn; }
    }
    if (kg < 4){
      float rg = sigmoidf_(fmaf(x0,wir0, fmaf(x1,wir1, br))  + mar);
      float zg = sigmoidf_(fmaf(x0,wiz0, fmaf(x1,wiz1, bz))  + maz);
      float ng = tanhf    (fmaf(x0,win0, fmaf(x1,win1, bin)) + rg*(man + bhn));
      float hp = hs[nr*H + jh];
      ATOM_STF(&enc[((size_t)n*L + t)*H + jh], (1.f - zg)*ng + zg*hp);
    }
    asm volatile("s_waitcnt vmcnt(0)" ::: "memory");
    __syncthreads();
    if (tid == 0) FLAG_ST(&fl[jb*32], t+1);
  }
}

// ============ persistent decoder: same structure, Wih·emb pre-tabulated ============
__global__ __attribute__((amdgpu_flat_work_group_size(512,512), amdgpu_waves_per_eu(2,2)))
void dec_persist(
    const float* __restrict__ enc, float* __restrict__ q_all,
    const int* __restrict__ tgt, const float* __restrict__ dgi,
    const float* __restrict__ Whh, const float* __restrict__ bhh,
    float* __restrict__ hn_out, int* __restrict__ flags){
  __shared__ __align__(16) float hs[4*H];
  const int tid = threadIdx.x;
  const int jh_l = tid >> 3;
  const int kg   = tid & 7;
  const int g  = blockIdx.x & 31;
  const int jb = blockIdx.x >> 5;
  const int jh = jb*64 + jh_l;
  const int n0 = g*4;
  int* fl = flags + g*8*32;

  float4 wr[16], wz[16], wn[16];
  #pragma unroll
  for (int i = 0; i < 16; ++i){
    const float* p0 = &Whh[(size_t)jh*H        + (kg + 8*i)*4];
    const float* p1 = &Whh[(size_t)(512+jh)*H  + (kg + 8*i)*4];
    const float* p2 = &Whh[(size_t)(1024+jh)*H + (kg + 8*i)*4];
    GLOAD4(wr[i], p0);
    GLOAD4(wz[i], p1);
    GLOAD4(wn[i], p2);
  }
  asm volatile("s_waitcnt vmcnt(0)" ::: "memory");

  const float bh_r = bhh[jh], bh_z = bhh[512+jh], bh_n = bhh[1024+jh];
  const int nr = kg & 3;
  const int n = n0 + nr;
  const int sr = tid >> 7;
  const int sv = tid & 127;

  for (int t = 0; t < T; ++t){
    int tok = (t == 0) ? 0 : tgt[n*T + (t-1)];
    float g0 = dgi[(size_t)tok*1536 + jh];
    float g1 = dgi[(size_t)tok*1536 + 512 + jh];
    float g2 = dgi[(size_t)tok*1536 + 1024 + jh];
    if (t == 0){
      ((float4*)hs)[tid] = *(const float4*)&enc[((size_t)(n0+sr)*L + (L-1))*H + sv*4];
      __syncthreads();
    } else {
      if (tid < 8){
        while (FLAG_LD(&fl[tid*32]) < t) __builtin_amdgcn_s_sleep(1);
      }
      __syncthreads();
      const float* srcp = &q_all[(size_t)(t-1)*NB*H + (size_t)(n0+sr)*H + sv*4];
      unsigned long long a = ATOM_LD8(srcp);
      unsigned long long b = ATOM_LD8(srcp+2);
      unsigned long long* dst = (unsigned long long*)hs;
      dst[(sr*128+sv)*2]   = a;
      dst[(sr*128+sv)*2+1] = b;
      __syncthreads();
    }

    float mar = 0.f, maz = 0.f, man = 0.f;
    #pragma unroll
    for (int nl = 0; nl < 4; ++nl){
      const float4* hb = (const float4*)&hs[nl*H];
      float pr = 0.f, pz = 0.f, pn = 0.f;
      #pragma unroll
      for (int i = 0; i < 16; ++i){
        float4 h4 = hb[kg + 8*i];
        pr = fmaf(h4.x,wr[i].x, fmaf(h4.y,wr[i].y, fmaf(h4.z,wr[i].z, fmaf(h4.w,wr[i].w, pr))));
        pz = fmaf(h4.x,wz[i].x, fmaf(h4.y,wz[i].y, fmaf(h4.z,wz[i].z, fmaf(h4.w,wz[i].w, pz))));
        pn = fmaf(h4.x,wn[i].x, fmaf(h4.y,wn[i].y, fmaf(h4.z,wn[i].z, fmaf(h4.w,wn[i].w, pn))));
      }
      #pragma unroll
      for (int off = 1; off < 8; off <<= 1){
        pr += __shfl_xor(pr, off);
        pz += __shfl_xor(pz, off);
        pn += __shfl_xor(pn, off);
      }
      if (kg == nl){ mar = pr; maz = pz; man = pn; }
    }
    if (kg < 4){
      float rg = sigmoidf_(g0 + mar + bh_r);
      float zg = sigmoidf_(g1 + maz + bh_z);
      float ng = tanhf    (g2 + rg*(man + bh_n));
      float hp = hs[nr*H + jh];
      float q  = (1.f - zg)*ng + zg*hp;
      ATOM_STF(&q_all[(size_t)t*NB*H + (size_t)n*H + jh], q);
      if (t == T-1) hn_out[(size_t)n*H + jh] = q;
    }
    asm volatile("s_waitcnt vmcnt(0)" ::: "memory");
    __syncthreads();
    if (tid == 0) FLAG_ST(&fl[jb*32], t+1);
  }
}

// ---------------- batched scores: s[n][t][l] = q[t][n][:] . enc[n][l][:] ------------
__global__ __launch_bounds__(256) void scores_kernel(
    const float* __restrict__ enc, const float* __restrict__ q_all,
    float* __restrict__ wout){
  int t0 = blockIdx.x * 16, l0 = blockIdx.y * 64, n = blockIdx.z;
  int tid = threadIdx.x;
  __shared__ __align__(16) float A[16][33];
  __shared__ __align__(16) float B[32][68];
  int t_l = tid >> 4, l_g = tid & 15;
  float4 acc = make_float4(0,0,0,0);
  for (int kc = 0; kc < 16; ++kc){
    __syncthreads();
    for (int e = tid; e < 512; e += 256){
      int r = e >> 5, k = e & 31;
      A[r][k] = q_all[(size_t)(t0+r)*NB*H + (size_t)n*H + kc*32 + k];
    }
    for (int e = tid; e < 2048; e += 256){
      int l = e >> 5, k = e & 31;
      B[k][l] = enc[((size_t)n*L + l0 + l)*H + kc*32 + k];
    }
    __syncthreads();
    #pragma unroll
    for (int kk = 0; kk < 32; ++kk){
      float a = A[t_l][kk];
      float4 b = *(const float4*)&B[kk][l_g*4];
      acc.x += a*b.x; acc.y += a*b.y; acc.z += a*b.z; acc.w += a*b.w;
    }
  }
  *(float4*)&wout[(size_t)n*T*L + (size_t)(t0+t_l)*L + l0 + l_g*4] = acc;
}

// ---------------- softmax rows of all_w in place (one wave per (n,t)) --------------
__global__ __launch_bounds__(64) void softmax_kernel(float* __restrict__ w){
  float* p = w + (size_t)blockIdx.x * L;
  int lane = threadIdx.x;
  float4 v0 = *(float4*)&p[lane*8];
  float4 v1 = *(float4*)&p[lane*8+4];
  float m = fmaxf(fmaxf(fmaxf(v0.x,v0.y),fmaxf(v0.z,v0.w)),
                  fmaxf(fmaxf(v1.x,v1.y),fmaxf(v1.z,v1.w)));
  for (int off = 32; off; off >>= 1) m = fmaxf(m, __shfl_xor(m, off));
  v0.x = expf(v0.x-m); v0.y = expf(v0.y-m); v0.z = expf(v0.z-m); v0.w = expf(v0.w-m);
  v1.x = expf(v1.x-m); v1.y = expf(v1.y-m); v1.z = expf(v1.z-m); v1.w = expf(v1.w-m);
  float s = v0.x+v0.y+v0.z+v0.w+v1.x+v1.y+v1.z+v1.w;
  for (int off = 32; off; off >>= 1) s += __shfl_xor(s, off);
  float inv = 1.f/s;
  v0.x*=inv; v0.y*=inv; v0.z*=inv; v0.w*=inv;
  v1.x*=inv; v1.y*=inv; v1.z*=inv; v1.w*=inv;
  *(float4*)&p[lane*8] = v0;
  *(float4*)&p[lane*8+4] = v1;
}

// ---------------- batched attn: a[t][n][h] = sum_l w[n][t][l] * enc[n][l][h] -------
__global__ __launch_bounds__(256) void attn_kernel(
    const float* __restrict__ enc, const float* __restrict__ w_in,
    float* __restrict__ attn_all){
  int t0 = blockIdx.x * 16, h0 = blockIdx.y * 64, n = blockIdx.z;
  int tid = threadIdx.x;
  __shared__ __align__(16) float A[16][33];
  __shared__ __align__(16) float B[32][64];
  int t_l = tid >> 4, h_g = tid & 15;
  float4 acc = make_float4(0,0,0,0);
  for (int lc = 0; lc < 16; ++lc){
    __syncthreads();
    for (int e = tid; e < 512; e += 256){
      int r = e >> 5, ll = e & 31;
      A[r][ll] = w_in[(size_t)n*T*L + (size_t)(t0+r)*L + lc*32 + ll];
    }
    for (int e = tid; e < 2048; e += 256){
      int ll = e >> 6, h = e & 63;
      B[ll][h] = enc[((size_t)n*L + lc*32 + ll)*H + h0 + h];
    }
    __syncthreads();
    #pragma unroll
    for (int ll = 0; ll < 32; ++ll){
      float a = A[t_l][ll];
      float4 b = *(const float4*)&B[ll][h_g*4];
      acc.x += a*b.x; acc.y += a*b.y; acc.z += a*b.z; acc.w += a*b.w;
    }
  }
  *(float4*)&attn_all[(size_t)(t0+t_l)*NB*H + (size_t)n*H + h0 + h_g*4] = acc;
}

// ---------------- output head: v[n][t][s] = c[s] + [q|attn] . M[:,s] ----------------
__global__ __launch_bounds__(256) void out_kernel(
    const float* __restrict__ q_all, const float* __restrict__ attn_all,
    const float4* __restrict__ M4, const float* __restrict__ c,
    float* __restrict__ vout){
  __shared__ __align__(16) float cat[4][1024];
  int tid = threadIdx.x;
  int row0 = blockIdx.x * 4;
  for (int e = tid; e < 4096; e += 256){
    int r = e >> 10, k = e & 1023;
    int row = row0 + r;
    int n = row >> 7, t = row & 127;
    cat[r][k] = (k < 512) ? q_all[(size_t)t*NB*H + (size_t)n*H + k]
                          : attn_all[(size_t)t*NB*H + (size_t)n*H + (k-512)];
  }
  __syncthreads();
  int r_l = tid >> 6, s = tid & 63;
  int row = row0 + r_l;
  int n = row >> 7, t = row & 127;
  float acc = c[s];
  #pragma unroll 4
  for (int k4 = 0; k4 < 256; ++k4){
    float4 cv = ((const float4*)&cat[r_l][0])[k4];
    float4 m = M4[k4*64 + s];
    acc += cv.x*m.x + cv.y*m.y + cv.z*m.z + cv.w*m.w;
  }
  vout[(size_t)n*T*S + (size_t)t*S + s] = acc;
}

extern "C" void kernel_launch(void* const* d_in, const int* in_sizes, int n_in,
                              void* d_out, int out_size, void* d_ws, size_t ws_size,
                              hipStream_t stream) {
  const float* x       = (const float*)d_in[0];
  const int*   target  = (const int*)d_in[1];
  const float* enc_Wih = (const float*)d_in[2];
  const float* enc_Whh = (const float*)d_in[3];
  const float* enc_bih = (const float*)d_in[4];
  const float* enc_bhh = (const float*)d_in[5];
  const float* dec_Wih = (const float*)d_in[6];
  const float* dec_Whh = (const float*)d_in[7];
  const float* dec_bih = (const float*)d_in[8];
  const float* dec_bhh = (const float*)d_in[9];
  const float* emb     = (const float*)d_in[10];
  const float* affW    = (const float*)d_in[11];
  const float* affB    = (const float*)d_in[12];
  const float* fcW     = (const float*)d_in[13];
  const float* fcB     = (const float*)d_in[14];

  float* ws      = (float*)d_ws;
  float* enc     = ws + OFF_ENC;
  float* q_all   = ws + OFF_Q;
  float* attn_al = ws + OFF_ATTN;
  float* dgi     = ws + OFF_DGI;
  float* M4f     = ws + OFF_M4;
  float* cb      = ws + OFF_C;
  int*   flg1    = (int*)(ws + OFF_FLG1);
  int*   flg2    = (int*)(ws + OFF_FLG2);

  float* vout   = (float*)d_out + OUT_V;
  float* hn_out = (float*)d_out + OUT_HN;
  float* w_all  = (float*)d_out + OUT_W;

  hipMemsetAsync(flg1, 0, 2*8192*sizeof(int), stream);   // flg1+flg2 contiguous
  prep_m_kernel<<<256, 256, 0, stream>>>(M4f, cb, affW, affB, fcW, fcB);
  dgi_kernel<<<64, 256, 0, stream>>>(dgi, dec_Wih, dec_bih, emb);

  {
    void* args[] = {(void*)&enc, (void*)&x, (void*)&enc_Wih, (void*)&enc_Whh,
                    (void*)&enc_bih, (void*)&enc_bhh, (void*)&flg1};
    hipLaunchCooperativeKernel((void*)enc_persist, dim3(256), dim3(512), args, 0, stream);
  }
  {
    void* args[] = {(void*)&enc, (void*)&q_all, (void*)&target, (void*)&dgi,
                    (void*)&dec_Whh, (void*)&dec_bhh, (void*)&hn_out, (void*)&flg2};
    hipLaunchCooperativeKernel((void*)dec_persist, dim3(256), dim3(512), args, 0, stream);
  }

  scores_kernel<<<dim3(8,8,NB), 256, 0, stream>>>(enc, q_all, w_all);
  softmax_kernel<<<NB*T, 64, 0, stream>>>(w_all);
  attn_kernel<<<dim3(8,8,NB), 256, 0, stream>>>(enc, w_all, attn_al);
  out_kernel<<<NB*T/4, 256, 0, stream>>>(q_all, attn_al, (const float4*)M4f, cb, vout);
}